// Round 1
// baseline (331.938 us; speedup 1.0000x reference)
//
#include <hip/hip_runtime.h>
#include <hip/hip_bf16.h>

typedef __hip_bfloat16 bf16;
typedef short s16x8 __attribute__((ext_vector_type(8)));
typedef float f32x4 __attribute__((ext_vector_type(4)));

static constexpr int NROWS = 8192;   // N in reference
static constexpr int DIM   = 256;    // IN_DIM == OUT_DIM == K

__device__ inline float to_f(float v) { return v; }
__device__ inline float to_f(bf16 v)  { return __bfloat162float(v); }
__device__ inline unsigned short f2bf(float f) {
    bf16 h = __float2bfloat16(f);
    return __builtin_bit_cast(unsigned short, h);
}

// ---------------------------------------------------------------------------
// Weight convert fp32 -> bf16. grid = 128, block = 256, 1 float4/thread.
//   blocks 0..63  : W1 -> W1b
//   blocks 64..127: W2 -> W2b
// ---------------------------------------------------------------------------
__global__ void convW_kernel(const float* __restrict__ W1, const float* __restrict__ W2,
                             bf16* __restrict__ W1b, bf16* __restrict__ W2b) {
    const int b = blockIdx.x;
    const float* src = (b < 64) ? W1 : W2;
    bf16*       dst = (b < 64) ? W1b : W2b;
    const int t = (b & 63) * 256 + threadIdx.x;          // 0..16383 float4s
    float4 v = ((const float4*)src)[t];
    ((ushort4*)dst)[t] = make_ushort4(f2bf(v.x), f2bf(v.y), f2bf(v.z), f2bf(v.w));
}

// ---------------------------------------------------------------------------
// Fused MLP layer: C = relu(A' @ W1^T + b1) @ W2^T + b2
//   A' = A                      if eps == 0   (fast path, always in bench)
//   A' = A + eps*(adj @ A)      otherwise     (slow inline fallback)
//
// grid = 8192/32 = 256 blocks, block = 256 thr = 4 waves. Block owns a
// 32-row slab; wave owns 64 cols in each phase. h (32x256 bf16) lives in
// LDS between phases — no HBM round-trip. W1/W2 fragments stream from
// global (L2-hot, 256 KB/block) straight into registers.
//
// Phase 1 is operand-SWAPPED (mfma(W1frag, xfrag) -> D[m=hcol][n=row]) so a
// lane's 4 acc values are k-contiguous h-cols -> one packed ds_write_b64
// per fragment (8/lane total), giving a row-major bf16 h-tile that phase 2
// reads back as s16x8 A-fragments (verified m89/m91 C/D mapping both ways).
// ---------------------------------------------------------------------------
template<typename TIN, bool OUTF32>
__global__ __launch_bounds__(256, 1)
void fused_mlp(const TIN* __restrict__ A, const float* __restrict__ adj,
               const float* __restrict__ eps_p,
               const bf16* __restrict__ W1, const float* __restrict__ b1,
               const bf16* __restrict__ W2, const float* __restrict__ b2,
               void* __restrict__ C) {
    constexpr int K = 256;
    constexpr int PITCH = 264;          // shorts/row; same alias class as proven kernel
    __shared__ short Xs[32][PITCH];     // input slab, bf16
    __shared__ short Hs[32][PITCH];     // hidden slab, bf16

    const int tid  = threadIdx.x;
    const int lane = tid & 63;
    const int wave = tid >> 6;          // 0..3
    const int lr = lane & 15;
    const int q  = lane >> 4;
    const int row0 = blockIdx.x * 32;
    const float eps = *eps_p;

    // ---- stage X tile: 32 rows x 256 -> bf16 LDS --------------------------
    if (eps == 0.0f) {
#pragma unroll
        for (int p = 0; p < 4; ++p) {
            const int id = p * 256 + tid;               // 0..1023 chunks of 8
            const int r  = id >> 5;
            const int c  = (id & 31) * 8;
            if constexpr (sizeof(TIN) == 4) {           // fp32 in: convert
                const float* src = (const float*)A + (size_t)(row0 + r) * K + c;
                float4 v0 = *(const float4*)(src);
                float4 v1 = *(const float4*)(src + 4);
                *(ushort4*)(&Xs[r][c])     = make_ushort4(f2bf(v0.x), f2bf(v0.y), f2bf(v0.z), f2bf(v0.w));
                *(ushort4*)(&Xs[r][c + 4]) = make_ushort4(f2bf(v1.x), f2bf(v1.y), f2bf(v1.z), f2bf(v1.w));
            } else {                                    // bf16 in: copy
                *(uint4*)(&Xs[r][c]) = *(const uint4*)((const bf16*)A + (size_t)(row0 + r) * K + c);
            }
        }
    } else {
        // slow correct fallback: aggregated rows (never taken in this bench)
        for (int r = 0; r < 32; ++r) {
            const int row = row0 + r;
            float s = 0.0f;
            const float* arow = adj + (size_t)row * NROWS;
            for (int k = 0; k < NROWS; ++k)
                s += arow[k] * to_f(A[(size_t)k * DIM + tid]);
            Xs[r][tid] = (short)f2bf(to_f(A[(size_t)row * DIM + tid]) + eps * s);
        }
    }
    __syncthreads();

    // ---- phase 1: h^T = W1 @ X^T (swapped operands) -----------------------
    // wave owns h-cols [wave*64, wave*64+64)
    f32x4 acc1[4][2] = {};
    const bf16* W1p = W1 + (size_t)(wave * 64 + lr) * K + q * 8;
#pragma unroll
    for (int kk = 0; kk < 8; ++kk) {
        s16x8 wf[4], xf[2];
#pragma unroll
        for (int i = 0; i < 4; ++i)
            wf[i] = *(const s16x8*)(W1p + (size_t)i * 16 * K + kk * 32);
#pragma unroll
        for (int j = 0; j < 2; ++j)
            xf[j] = *(const s16x8*)(&Xs[j * 16 + lr][kk * 32 + q * 8]);
#pragma unroll
        for (int i = 0; i < 4; ++i)
#pragma unroll
            for (int j = 0; j < 2; ++j)
                acc1[i][j] = __builtin_amdgcn_mfma_f32_16x16x32_bf16(
                    wf[i], xf[j], acc1[i][j], 0, 0, 0);
    }

    // epilogue 1: lane holds hcol = wave*64 + i*16 + q*4 + r  (k-contiguous!),
    // xrow = j*16 + lr. bias+relu+cvt, one b64 write per (i,j).
#pragma unroll
    for (int i = 0; i < 4; ++i) {
        const int hc = wave * 64 + i * 16 + q * 4;
        const float4 bv = *(const float4*)(b1 + hc);
#pragma unroll
        for (int j = 0; j < 2; ++j) {
            ushort4 hv;
            hv.x = f2bf(fmaxf(acc1[i][j][0] + bv.x, 0.0f));
            hv.y = f2bf(fmaxf(acc1[i][j][1] + bv.y, 0.0f));
            hv.z = f2bf(fmaxf(acc1[i][j][2] + bv.z, 0.0f));
            hv.w = f2bf(fmaxf(acc1[i][j][3] + bv.w, 0.0f));
            *(ushort4*)(&Hs[j * 16 + lr][hc]) = hv;
        }
    }
    __syncthreads();

    // ---- phase 2: Y = H @ W2^T (normal orientation) -----------------------
    // wave owns y-cols [wave*64, wave*64+64)
    f32x4 acc2[2][4] = {};
    const bf16* W2p = W2 + (size_t)(wave * 64 + lr) * K + q * 8;
#pragma unroll
    for (int kk = 0; kk < 8; ++kk) {
        s16x8 hf[2], wf[4];
#pragma unroll
        for (int j = 0; j < 4; ++j)
            wf[j] = *(const s16x8*)(W2p + (size_t)j * 16 * K + kk * 32);
#pragma unroll
        for (int i = 0; i < 2; ++i)
            hf[i] = *(const s16x8*)(&Hs[i * 16 + lr][kk * 32 + q * 8]);
#pragma unroll
        for (int i = 0; i < 2; ++i)
#pragma unroll
            for (int j = 0; j < 4; ++j)
                acc2[i][j] = __builtin_amdgcn_mfma_f32_16x16x32_bf16(
                    hf[i], wf[j], acc2[i][j], 0, 0, 0);
    }

    // epilogue 2: row = row0 + i*16 + q*4 + r, col = wave*64 + j*16 + lr
#pragma unroll
    for (int i = 0; i < 2; ++i) {
#pragma unroll
        for (int j = 0; j < 4; ++j) {
            const int col = wave * 64 + j * 16 + lr;
            const float bv = b2[col];
#pragma unroll
            for (int r = 0; r < 4; ++r) {
                const int row = row0 + i * 16 + q * 4 + r;
                float v = acc2[i][j][r] + bv;
                if (OUTF32) ((float*)C)[(size_t)row * DIM + col] = v;
                else        ((bf16*)C)[(size_t)row * DIM + col] = __float2bfloat16(v);
            }
        }
    }
}

// ---------------------------------------------------------------------------
extern "C" void kernel_launch(void* const* d_in, const int* in_sizes, int n_in,
                              void* d_out, int out_size, void* d_ws, size_t ws_size,
                              hipStream_t stream) {
    const float* x   = (const float*)d_in[0];
    const float* adj = (const float*)d_in[1];
    const float* W1  = (const float*)d_in[2];
    const float* b1  = (const float*)d_in[3];
    const float* W2  = (const float*)d_in[4];
    const float* b2  = (const float*)d_in[5];
    const float* eps = (const float*)d_in[6];
    float* out = (float*)d_out;

    char* ws = (char*)d_ws;
    bf16* W1b   = (bf16*)ws;  ws += (size_t)DIM * DIM * 2;
    bf16* W2b   = (bf16*)ws;  ws += (size_t)DIM * DIM * 2;
    bf16* bufY1 = (bf16*)ws;  ws += (size_t)NROWS * DIM * 2;

    convW_kernel<<<128, 256, 0, stream>>>(W1, W2, W1b, W2b);
    // layer 0: x (fp32) -> bufY1 (bf16)
    fused_mlp<float, false><<<NROWS / 32, 256, 0, stream>>>(x, adj, eps, W1b, b1, W2b, b2, bufY1);
    // layer 1: bufY1 (bf16) -> out (fp32)
    fused_mlp<bf16,  true ><<<NROWS / 32, 256, 0, stream>>>(bufY1, adj, eps, W1b, b1, W2b, b2, out);
}

// Round 2
// 328.228 us; speedup vs baseline: 1.0113x; 1.0113x over previous
//
#include <hip/hip_runtime.h>
#include <hip/hip_bf16.h>

typedef __hip_bfloat16 bf16;
typedef short s16x8 __attribute__((ext_vector_type(8)));
typedef float f32x4 __attribute__((ext_vector_type(4)));

static constexpr int NROWS = 8192;   // N in reference
static constexpr int DIM   = 256;    // IN_DIM == OUT_DIM == K
static constexpr int KDIM  = 256;
static constexpr int PITCH = 264;    // shorts/row: 132 dwords -> 4-bank stride, 2-way alias (free, m136)

__device__ inline float to_f(float v) { return v; }
__device__ inline float to_f(bf16 v)  { return __bfloat162float(v); }
__device__ inline unsigned short f2bf(float f) {
    bf16 h = __float2bfloat16(f);
    return __builtin_bit_cast(unsigned short, h);
}

// ---------------------------------------------------------------------------
// k1: weight convert (always) + agg0 fallback (eps != 0 only, never in bench).
// Verbatim round-0 proven kernel. grid = 128, block = 256.
// ---------------------------------------------------------------------------
__global__ void agg0_convW_kernel(const float* __restrict__ x, const float* __restrict__ adj,
                                  const float* __restrict__ W1, const float* __restrict__ W2,
                                  const float* __restrict__ eps_p,
                                  bf16* __restrict__ W1b, bf16* __restrict__ W2b,
                                  float* __restrict__ y) {
    {
        const int b = blockIdx.x;
        const float* src = (b < 64) ? W1 : W2;
        bf16*       dst = (b < 64) ? W1b : W2b;
        const int t = (b & 63) * 256 + threadIdx.x;      // 0..16383 float4s
        float4 v = ((const float4*)src)[t];
        ((ushort4*)dst)[t] = make_ushort4(f2bf(v.x), f2bf(v.y), f2bf(v.z), f2bf(v.w));
    }
    const float eps = *eps_p;
    if (eps == 0.0f) return;                             // fast path: done
    const size_t total = (size_t)NROWS * DIM;
    for (size_t e = (size_t)blockIdx.x * blockDim.x + threadIdx.x;
         e < total;
         e += (size_t)gridDim.x * blockDim.x) {
        const int i = (int)(e >> 8);                     // DIM = 256
        const int j = (int)(e & 255);
        float s = 0.0f;
        const float* arow = adj + (size_t)i * NROWS;
        for (int k = 0; k < NROWS; ++k)
            s += arow[k] * x[(size_t)k * DIM + j];
        y[e] = x[e] + eps * s;
    }
}

// ---------------------------------------------------------------------------
// MLP phase, swapped orientation: D = W_frag (A-op) x Act_frag (B-op).
// D mapping (verified m89/m91): M (out-col) = i*16 + q*4 + reg, N (slab row)
// = j*16 + lr. Lane's 4 acc values are out-col-contiguous -> packed stores.
// Weights are register-resident (wf), activations read from LDS.
// ---------------------------------------------------------------------------
template<bool RELU>
__device__ __forceinline__ void mlp_phase_lds(const s16x8 (&wf)[8][4],
                                              short (*src)[PITCH], short (*dst)[PITCH],
                                              const float* __restrict__ bias,
                                              int wave, int lr, int q) {
    f32x4 acc[4][2] = {};
#pragma unroll
    for (int kk = 0; kk < 8; ++kk) {
        s16x8 xf[2];
#pragma unroll
        for (int j = 0; j < 2; ++j)
            xf[j] = *(const s16x8*)(&src[j * 16 + lr][kk * 32 + q * 8]);
#pragma unroll
        for (int i = 0; i < 4; ++i)
#pragma unroll
            for (int j = 0; j < 2; ++j)
                acc[i][j] = __builtin_amdgcn_mfma_f32_16x16x32_bf16(
                    wf[kk][i], xf[j], acc[i][j], 0, 0, 0);
    }
#pragma unroll
    for (int i = 0; i < 4; ++i) {
        const int oc = wave * 64 + i * 16 + q * 4;       // out-col base (k-contig)
        const float4 bv = *(const float4*)(bias + oc);
#pragma unroll
        for (int j = 0; j < 2; ++j) {
            float v0 = acc[i][j][0] + bv.x;
            float v1 = acc[i][j][1] + bv.y;
            float v2 = acc[i][j][2] + bv.z;
            float v3 = acc[i][j][3] + bv.w;
            if (RELU) {
                v0 = fmaxf(v0, 0.0f); v1 = fmaxf(v1, 0.0f);
                v2 = fmaxf(v2, 0.0f); v3 = fmaxf(v3, 0.0f);
            }
            *(ushort4*)(&dst[j * 16 + lr][oc]) =
                make_ushort4(f2bf(v0), f2bf(v1), f2bf(v2), f2bf(v3));
        }
    }
}

// Same phase but final: bias (no relu), store to global (fp32 or bf16), packed.
template<bool OUTF32>
__device__ __forceinline__ void mlp_phase_out(const s16x8 (&wf)[8][4],
                                              short (*src)[PITCH],
                                              const float* __restrict__ bias,
                                              void* __restrict__ C,
                                              int wave, int lr, int q, int row0) {
    f32x4 acc[4][2] = {};
#pragma unroll
    for (int kk = 0; kk < 8; ++kk) {
        s16x8 xf[2];
#pragma unroll
        for (int j = 0; j < 2; ++j)
            xf[j] = *(const s16x8*)(&src[j * 16 + lr][kk * 32 + q * 8]);
#pragma unroll
        for (int i = 0; i < 4; ++i)
#pragma unroll
            for (int j = 0; j < 2; ++j)
                acc[i][j] = __builtin_amdgcn_mfma_f32_16x16x32_bf16(
                    wf[kk][i], xf[j], acc[i][j], 0, 0, 0);
    }
#pragma unroll
    for (int i = 0; i < 4; ++i) {
        const int oc = wave * 64 + i * 16 + q * 4;
        const float4 bv = *(const float4*)(bias + oc);
#pragma unroll
        for (int j = 0; j < 2; ++j) {
            const int row = row0 + j * 16 + lr;
            float v0 = acc[i][j][0] + bv.x;
            float v1 = acc[i][j][1] + bv.y;
            float v2 = acc[i][j][2] + bv.z;
            float v3 = acc[i][j][3] + bv.w;
            if (OUTF32) {
                float4 o; o.x = v0; o.y = v1; o.z = v2; o.w = v3;
                *(float4*)(&((float*)C)[(size_t)row * DIM + oc]) = o;
            } else {
                *(ushort4*)(&((bf16*)C)[(size_t)row * DIM + oc]) =
                    make_ushort4(f2bf(v0), f2bf(v1), f2bf(v2), f2bf(v3));
            }
        }
    }
}

// Load this wave's 64-row weight fragment set into registers (32 KB/wave/matrix
// as bf16 -> 128 VGPRs per matrix). Fragment layout identical for A/B operands.
__device__ __forceinline__ void load_wfrags(const bf16* __restrict__ W,
                                            s16x8 (&wf)[8][4],
                                            int wave, int lr, int q) {
    const bf16* Wp = W + (size_t)(wave * 64 + lr) * KDIM + q * 8;
#pragma unroll
    for (int kk = 0; kk < 8; ++kk)
#pragma unroll
        for (int i = 0; i < 4; ++i)
            wf[kk][i] = *(const s16x8*)(Wp + (size_t)i * 16 * KDIM + kk * 32);
}

// ---------------------------------------------------------------------------
// k2: mega kernel — with eps==0 the ENTIRE 2-layer GIN is row-local, so one
// block does all 4 GEMMs for its 32-row slab, activations ping-ponging in LDS
// (Xs <-> Hs), weights register-resident across all phases. Zero global loads
// inside any MFMA loop; only HBM traffic is x in (fp32) and out (fp32).
// grid = 8192/32 = 256 blocks, block = 256 thr = 4 waves (wave owns 64 cols).
// ---------------------------------------------------------------------------
__global__ __launch_bounds__(256, 1)
void mega_gin(const float* __restrict__ x, const float* __restrict__ eps_p,
              const bf16* __restrict__ W1, const float* __restrict__ b1,
              const bf16* __restrict__ W2, const float* __restrict__ b2,
              float* __restrict__ out) {
    if (*eps_p != 0.0f) return;                          // fallback kernels handle it
    __shared__ short Xs[32][PITCH];
    __shared__ short Hs[32][PITCH];

    const int tid  = threadIdx.x;
    const int lane = tid & 63;
    const int wave = tid >> 6;
    const int lr = lane & 15;
    const int q  = lane >> 4;
    const int row0 = blockIdx.x * 32;

    // weights once, held across all 4 phases (256 VGPRs)
    s16x8 w1f[8][4], w2f[8][4];
    load_wfrags(W1, w1f, wave, lr, q);
    load_wfrags(W2, w2f, wave, lr, q);

    // stage x slab: 32 rows x 256 fp32 -> bf16 LDS
#pragma unroll
    for (int p = 0; p < 4; ++p) {
        const int id = p * 256 + tid;                    // 0..1023 chunks of 8
        const int r  = id >> 5;
        const int c  = (id & 31) * 8;
        const float* src = x + (size_t)(row0 + r) * KDIM + c;
        float4 v0 = *(const float4*)(src);
        float4 v1 = *(const float4*)(src + 4);
        *(ushort4*)(&Xs[r][c])     = make_ushort4(f2bf(v0.x), f2bf(v0.y), f2bf(v0.z), f2bf(v0.w));
        *(ushort4*)(&Xs[r][c + 4]) = make_ushort4(f2bf(v1.x), f2bf(v1.y), f2bf(v1.z), f2bf(v1.w));
    }
    __syncthreads();

    mlp_phase_lds<true >(w1f, Xs, Hs, b1, wave, lr, q);  // h1 = relu(x W1^T + b1)
    __syncthreads();
    mlp_phase_lds<false>(w2f, Hs, Xs, b2, wave, lr, q);  // y1 = h1 W2^T + b2
    __syncthreads();
    mlp_phase_lds<true >(w1f, Xs, Hs, b1, wave, lr, q);  // h2 = relu(y1 W1^T + b1)
    __syncthreads();
    mlp_phase_out<true >(w2f, Hs, b2, out, wave, lr, q, row0);  // out = h2 W2^T + b2
}

// ---------------------------------------------------------------------------
// k3/k4: eps != 0 fallback (never taken in this bench; early-exits otherwise).
// One MLP layer per launch; optional inline aggregation on the staged slab.
//   k3: A = agg0 buffer (fp32, pre-aggregated by k1), DO_AGG=false -> mid
//   k4: A = mid (bf16), DO_AGG=true (computes x + eps*(adj@x) inline) -> out
// ---------------------------------------------------------------------------
template<typename TIN, bool OUTF32, bool DO_AGG>
__global__ __launch_bounds__(256, 1)
void fb_mlp(const TIN* __restrict__ A, const float* __restrict__ adj,
            const float* __restrict__ eps_p,
            const bf16* __restrict__ W1, const float* __restrict__ b1,
            const bf16* __restrict__ W2, const float* __restrict__ b2,
            void* __restrict__ C) {
    const float eps = *eps_p;
    if (eps == 0.0f) return;                             // mega handled it
    __shared__ short Xs[32][PITCH];
    __shared__ short Hs[32][PITCH];

    const int tid  = threadIdx.x;
    const int lane = tid & 63;
    const int wave = tid >> 6;
    const int lr = lane & 15;
    const int q  = lane >> 4;
    const int row0 = blockIdx.x * 32;

    s16x8 w1f[8][4], w2f[8][4];
    load_wfrags(W1, w1f, wave, lr, q);
    load_wfrags(W2, w2f, wave, lr, q);

    if (DO_AGG) {
        for (int r = 0; r < 32; ++r) {                   // slow, correctness-only
            const int row = row0 + r;
            float s = 0.0f;
            const float* arow = adj + (size_t)row * NROWS;
            for (int k = 0; k < NROWS; ++k)
                s += arow[k] * to_f(A[(size_t)k * DIM + tid]);
            Xs[r][tid] = (short)f2bf(to_f(A[(size_t)row * DIM + tid]) + eps * s);
        }
    } else {
#pragma unroll
        for (int p = 0; p < 4; ++p) {
            const int id = p * 256 + tid;
            const int r  = id >> 5;
            const int c  = (id & 31) * 8;
            if constexpr (sizeof(TIN) == 4) {
                const float* src = (const float*)A + (size_t)(row0 + r) * KDIM + c;
                float4 v0 = *(const float4*)(src);
                float4 v1 = *(const float4*)(src + 4);
                *(ushort4*)(&Xs[r][c])     = make_ushort4(f2bf(v0.x), f2bf(v0.y), f2bf(v0.z), f2bf(v0.w));
                *(ushort4*)(&Xs[r][c + 4]) = make_ushort4(f2bf(v1.x), f2bf(v1.y), f2bf(v1.z), f2bf(v1.w));
            } else {
                *(uint4*)(&Xs[r][c]) = *(const uint4*)((const bf16*)A + (size_t)(row0 + r) * KDIM + c);
            }
        }
    }
    __syncthreads();

    mlp_phase_lds<true >(w1f, Xs, Hs, b1, wave, lr, q);
    __syncthreads();
    mlp_phase_out<OUTF32>(w2f, Hs, b2, C, wave, lr, q, row0);
}

// ---------------------------------------------------------------------------
extern "C" void kernel_launch(void* const* d_in, const int* in_sizes, int n_in,
                              void* d_out, int out_size, void* d_ws, size_t ws_size,
                              hipStream_t stream) {
    const float* x   = (const float*)d_in[0];
    const float* adj = (const float*)d_in[1];
    const float* W1  = (const float*)d_in[2];
    const float* b1  = (const float*)d_in[3];
    const float* W2  = (const float*)d_in[4];
    const float* b2  = (const float*)d_in[5];
    const float* eps = (const float*)d_in[6];
    float* out = (float*)d_out;

    char* ws = (char*)d_ws;
    bf16*  W1b  = (bf16*)ws;  ws += (size_t)DIM * DIM * 2;
    bf16*  W2b  = (bf16*)ws;  ws += (size_t)DIM * DIM * 2;
    float* agg0 = (float*)ws; ws += (size_t)NROWS * DIM * 4;
    bf16*  mid  = (bf16*)ws;  ws += (size_t)NROWS * DIM * 2;

    // k1: W fp32->bf16 (+ agg0 when eps != 0)
    agg0_convW_kernel<<<128, 256, 0, stream>>>(x, adj, W1, W2, eps, W1b, W2b, agg0);
    // k2: full 2-layer fast path (eps == 0)
    mega_gin<<<NROWS / 32, 256, 0, stream>>>(x, eps, W1b, b1, W2b, b2, out);
    // k3/k4: eps != 0 fallback chain (early-exit otherwise)
    fb_mlp<float, false, false><<<NROWS / 32, 256, 0, stream>>>(agg0, adj, eps, W1b, b1, W2b, b2, mid);
    fb_mlp<bf16,  true,  true ><<<NROWS / 32, 256, 0, stream>>>(mid,  adj, eps, W1b, b1, W2b, b2, out);
}